// Round 4
// baseline (471.815 us; speedup 1.0000x reference)
//
#include <hip/hip_runtime.h>
#include <hip/hip_bf16.h>

// Problem constants (B=1)
#define T_ 8
#define H_ 64
#define W_ 64
#define C_ 64
#define HW_ (H_ * W_)          // 4096
#define THW_ (T_ * H_ * W_)    // 32768
#define KTAPS 27
#define KDIM (C_ * KTAPS)      // 1728
#define NOFF 54

typedef __bf16 bf16x8 __attribute__((ext_vector_type(8)));
typedef float floatx4 __attribute__((ext_vector_type(4)));

// ---------------------------------------------------------------------------
// prep: weight transforms (all to bf16, B-fragment-friendly [cout][tap*64+cin])
// ---------------------------------------------------------------------------
__global__ void prep_kernel(const float* __restrict__ w1, const float* __restrict__ woff,
                            const float* __restrict__ wd, const float* __restrict__ wr,
                            __hip_bfloat16* __restrict__ wT1b, __hip_bfloat16* __restrict__ wToffb,
                            __hip_bfloat16* __restrict__ wdTb, __hip_bfloat16* __restrict__ wrTb) {
    int i = blockIdx.x * 256 + threadIdx.x;
    if (i < C_ * KDIM) {
        int k = i % KDIM;          // k = tap*64 + cin
        int co = i / KDIM;
        int tap = k >> 6, cin = k & 63;
        wT1b[i] = __float2bfloat16(w1[(co * C_ + cin) * KTAPS + tap]);
        wToffb[i] = (co < NOFF) ? __float2bfloat16(woff[(co * C_ + cin) * KTAPS + tap])
                                : __float2bfloat16(0.f);
        wdTb[i] = __float2bfloat16(wd[(co * C_ + cin) * KTAPS + tap]);
    }
    if (i < C_ * C_) wrTb[i] = __float2bfloat16(wr[i]);
}

// ---------------------------------------------------------------------------
// x (64,T,H,W) fp32 cf -> xcl (T,H,W,64) bf16 cl, via LDS 64x64 transpose tile
// ---------------------------------------------------------------------------
__global__ __launch_bounds__(256) void to_cl_kernel(const float* __restrict__ x,
                                                    __hip_bfloat16* __restrict__ xcl) {
    __shared__ float tile[64][65];
    const int pos0 = blockIdx.x * 64;
    const int tid = threadIdx.x;
    for (int i = tid; i < 4096; i += 256) {          // coalesced read: p contiguous
        int ch = i >> 6, p = i & 63;
        tile[ch][p] = x[ch * THW_ + pos0 + p];
    }
    __syncthreads();
    for (int i = tid; i < 4096; i += 256) {          // coalesced write: ch contiguous
        int p = i >> 6, ch = i & 63;
        xcl[(pos0 + p) * C_ + ch] = __float2bfloat16(tile[ch][p]);
    }
}

// ---------------------------------------------------------------------------
// MFMA implicit-GEMM 3x3x3 conv, pad=1.
//  Block = 256 thr = 4 waves; covers (t,h) fixed, 16-w strip q, all 64 couts.
//  Wave wv: couts [wv*16,..+16) x 16 positions (one 16x16 MFMA tile, m=1).
//  Grid: T*H*4 = 2048 blocks.
// ---------------------------------------------------------------------------
template <bool CONV1>
__global__ __launch_bounds__(256) void conv_mfma_kernel(
    const __hip_bfloat16* __restrict__ in_cl,
    const __hip_bfloat16* __restrict__ wT,
    const float* __restrict__ bias,
    __hip_bfloat16* __restrict__ out_cl_b16, // CONV1: (T,H,W,64)
    float* __restrict__ out_cf,              // !CONV1: (NCO,T,H,W)
    int nco) {
    __shared__ float ts[CONV1 ? 16 * 68 : 1];

    const int tid = threadIdx.x;
    const int wv = tid >> 6;
    const int lane = tid & 63;
    const int l15 = lane & 15;
    const int quad = lane >> 4;
    const int q = blockIdx.x & 3;            // w-quarter
    const int h = (blockIdx.x >> 2) & 63;
    const int t = blockIdx.x >> 8;
    const int n = wv * 16 + l15;             // this lane's cout

    floatx4 acc = (floatx4){0.f, 0.f, 0.f, 0.f};

    const __hip_bfloat16* wB = wT + n * KDIM + quad * 8;   // + tap*64 (+32 for s=1)
    const int wl = q * 16 + l15 - 1;                        // w offset before +kw
    const bf16x8 zfrag = {};

#pragma unroll 1
    for (int kt = 0; kt < 3; ++kt) {
        const int t_in = t + kt - 1;
        if ((unsigned)t_in >= T_) continue;                 // uniform
#pragma unroll 1
        for (int kh = 0; kh < 3; ++kh) {
            const int h_in = h + kh - 1;
            if ((unsigned)h_in >= H_) continue;             // uniform
            const int rowbase = (t_in * HW_ + h_in * W_);
#pragma unroll
            for (int kw = 0; kw < 3; ++kw) {
                const int tap = kt * 9 + kh * 3 + kw;
                const bf16x8 b0 = *(const bf16x8*)(wB + tap * 64);
                const bf16x8 b1 = *(const bf16x8*)(wB + tap * 64 + 32);
                const int w_in = wl + kw;
                const bool v = (unsigned)w_in < W_;         // per-lane (edge lanes)
                const int wc = v ? w_in : 0;
                const __hip_bfloat16* ap = in_cl + (rowbase + wc) * C_ + quad * 8;
                bf16x8 a0 = *(const bf16x8*)(ap);
                bf16x8 a1 = *(const bf16x8*)(ap + 32);
                a0 = v ? a0 : zfrag;
                a1 = v ? a1 : zfrag;
                acc = __builtin_amdgcn_mfma_f32_16x16x32_bf16(a0, b0, acc, 0, 0, 0);
                acc = __builtin_amdgcn_mfma_f32_16x16x32_bf16(a1, b1, acc, 0, 0, 0);
            }
        }
    }

    const int posbase = t * HW_ + h * W_ + q * 16;   // (t,h, q*16)

    if constexpr (CONV1) {
        const float bv = bias[n];
#pragma unroll
        for (int r = 0; r < 4; ++r) {
            float v = acc[r] + bv;
            v = (v >= 0.f) ? v : 0.01f * v;              // lrelu
            ts[(quad * 4 + r) * 68 + n] = v;             // [localpos][cout], pad 68
        }
        __syncthreads();
        // cooperative coalesced channel-last bf16 stores: 16 pos x 64 ch
        {
            const int p = tid >> 4, cg = tid & 15;       // 256 = 16x16 chunks of 4ch
            const float4 v4 = *(const float4*)&ts[p * 68 + cg * 4];
            __hip_bfloat16 hb[4] = {__float2bfloat16(v4.x), __float2bfloat16(v4.y),
                                    __float2bfloat16(v4.z), __float2bfloat16(v4.w)};
            *(uint2*)&out_cl_b16[(posbase + p) * C_ + cg * 4] = *(const uint2*)hb;
        }
    } else {
        if (n < nco) {
            const float bv = bias[n];
            floatx4 v = acc;
            v[0] += bv; v[1] += bv; v[2] += bv; v[3] += bv;
            *(floatx4*)&out_cf[n * THW_ + posbase + quad * 4] = v;
        }
    }
}

// ---------------------------------------------------------------------------
// MFMA deformable conv + bias + lrelu + fused 1x1 residual (also MFMA).
//  Block = (t,h,w-quarter); wave = 16 couts x 16 positions. Grid T*H*4.
// ---------------------------------------------------------------------------
__global__ __launch_bounds__(256) void deform_mfma_kernel(
    const __hip_bfloat16* __restrict__ y1b, const float* __restrict__ off,
    const __hip_bfloat16* __restrict__ wdTb, const float* __restrict__ bd,
    const __hip_bfloat16* __restrict__ xclb, const __hip_bfloat16* __restrict__ wrTb,
    const float* __restrict__ br, float* __restrict__ out) {
    const int tid = threadIdx.x;
    const int wv = tid >> 6;
    const int lane = tid & 63;
    const int l15 = lane & 15;
    const int quad = lane >> 4;
    const int q = blockIdx.x & 3;
    const int h = (blockIdx.x >> 2) & 63;
    const int t = blockIdx.x >> 8;
    const int n = wv * 16 + l15;            // this lane's cout
    const int posbase = t * HW_ + h * W_ + q * 16;
    const int w_ = q * 16 + l15;            // this lane's A-row position

    floatx4 acc = (floatx4){0.f, 0.f, 0.f, 0.f};
    floatx4 racc = (floatx4){0.f, 0.f, 0.f, 0.f};

    // ---- residual 1x1 conv on x: 2 MFMAs ----
    {
        const __hip_bfloat16* wrB = wrTb + n * C_ + quad * 8;
        const bf16x8 rb0 = *(const bf16x8*)(wrB);
        const bf16x8 rb1 = *(const bf16x8*)(wrB + 32);
        const __hip_bfloat16* ap = xclb + (posbase + l15) * C_ + quad * 8;
        const bf16x8 a0 = *(const bf16x8*)(ap);
        const bf16x8 a1 = *(const bf16x8*)(ap + 32);
        racc = __builtin_amdgcn_mfma_f32_16x16x32_bf16(a0, rb0, racc, 0, 0, 0);
        racc = __builtin_amdgcn_mfma_f32_16x16x32_bf16(a1, rb1, racc, 0, 0, 0);
    }

    // ---- deform taps ----
    const __hip_bfloat16* wB = wdTb + n * KDIM + quad * 8;

#pragma unroll 1
    for (int k = 0; k < KTAPS; ++k) {
        const int kt = k / 9, kh = (k / 3) % 3, kw = k % 3;
        const int t_in = t - 1 + kt;
        if ((unsigned)t_in >= T_) continue;                 // block-uniform

        const bf16x8 b0 = *(const bf16x8*)(wB + k * 64);
        const bf16x8 b1 = *(const bf16x8*)(wB + k * 64 + 32);
        const float dh = off[(2 * k) * THW_ + posbase + l15];
        const float dw = off[(2 * k + 1) * THW_ + posbase + l15];
        const int tb = t_in * HW_;

        const float hs = (float)(h - 1 + kh) + dh;
        const float wsv = (float)(w_ - 1 + kw) + dw;
        const float h0f = floorf(hs), w0f = floorf(wsv);
        const float fh = hs - h0f, fw = wsv - w0f;
        const int h0i = (int)h0f, w0i = (int)w0f;
        const int h1i = h0i + 1, w1i = w0i + 1;
        const float m_h0 = ((unsigned)h0i < H_) ? 1.f : 0.f;
        const float m_h1 = ((unsigned)h1i < H_) ? 1.f : 0.f;
        const float m_w0 = ((unsigned)w0i < W_) ? 1.f : 0.f;
        const float m_w1 = ((unsigned)w1i < W_) ? 1.f : 0.f;
        const float w00 = (1.f - fh) * (1.f - fw) * m_h0 * m_w0;
        const float w01 = (1.f - fh) * fw * m_h0 * m_w1;
        const float w10 = fh * (1.f - fw) * m_h1 * m_w0;
        const float w11 = fh * fw * m_h1 * m_w1;
        const int h0c = min(max(h0i, 0), H_ - 1);
        const int h1c = min(max(h1i, 0), H_ - 1);
        const int w0c = min(max(w0i, 0), W_ - 1);
        const int w1c = min(max(w1i, 0), W_ - 1);

        const __hip_bfloat16* p00 = y1b + (tb + h0c * W_ + w0c) * C_ + quad * 8;
        const __hip_bfloat16* p01 = y1b + (tb + h0c * W_ + w1c) * C_ + quad * 8;
        const __hip_bfloat16* p10 = y1b + (tb + h1c * W_ + w0c) * C_ + quad * 8;
        const __hip_bfloat16* p11 = y1b + (tb + h1c * W_ + w1c) * C_ + quad * 8;

#pragma unroll
        for (int s = 0; s < 2; ++s) {
            union { bf16x8 v; __hip_bfloat16 e[8]; } u00, u01, u10, u11, ua;
            u00.v = *(const bf16x8*)(p00 + s * 32);
            u01.v = *(const bf16x8*)(p01 + s * 32);
            u10.v = *(const bf16x8*)(p10 + s * 32);
            u11.v = *(const bf16x8*)(p11 + s * 32);
#pragma unroll
            for (int j = 0; j < 8; ++j) {
                float f = w00 * __bfloat162float(u00.e[j]) + w01 * __bfloat162float(u01.e[j]) +
                          w10 * __bfloat162float(u10.e[j]) + w11 * __bfloat162float(u11.e[j]);
                ua.e[j] = __float2bfloat16(f);
            }
            acc = __builtin_amdgcn_mfma_f32_16x16x32_bf16(ua.v, s ? b1 : b0, acc, 0, 0, 0);
        }
    }

    // ---- epilogue: lrelu(deform + bd) + (residual + br) ----
    const float bdv = bd[n];
    const float brv = br[n];
    floatx4 o;
#pragma unroll
    for (int r = 0; r < 4; ++r) {
        float v = acc[r] + bdv;
        v = (v >= 0.f) ? v : 0.01f * v;
        o[r] = v + racc[r] + brv;
    }
    *(floatx4*)&out[n * THW_ + posbase + quad * 4] = o;
}

// ---------------------------------------------------------------------------
extern "C" void kernel_launch(void* const* d_in, const int* in_sizes, int n_in,
                              void* d_out, int out_size, void* d_ws, size_t ws_size,
                              hipStream_t stream) {
    const float* x    = (const float*)d_in[0];
    const float* W1   = (const float*)d_in[1];
    const float* b1   = (const float*)d_in[2];
    const float* Woff = (const float*)d_in[3];
    const float* boff = (const float*)d_in[4];
    const float* Wd   = (const float*)d_in[5];
    const float* bd   = (const float*)d_in[6];
    const float* Wr   = (const float*)d_in[7];
    const float* br   = (const float*)d_in[8];
    float* out = (float*)d_out;

    float* ws = (float*)d_ws;
    float* offcf = ws;                                         // 1,769,472 f
    __hip_bfloat16* xclb   = (__hip_bfloat16*)(ws + 1769472);  // 2,097,152 bf16
    __hip_bfloat16* y1b    = (__hip_bfloat16*)(ws + 2818048);  // 2,097,152 bf16
    __hip_bfloat16* wT1b   = (__hip_bfloat16*)(ws + 3866624);  //   110,592 bf16
    __hip_bfloat16* wToffb = (__hip_bfloat16*)(ws + 3921920);  //   110,592 bf16
    __hip_bfloat16* wdTb   = (__hip_bfloat16*)(ws + 3977216);  //   110,592 bf16
    __hip_bfloat16* wrTb   = (__hip_bfloat16*)(ws + 4032512);  //     4,096 bf16
    // total ~16.1 MB

    prep_kernel<<<(C_ * KDIM + 255) / 256, 256, 0, stream>>>(
        W1, Woff, Wd, Wr, wT1b, wToffb, wdTb, wrTb);

    to_cl_kernel<<<THW_ / 64, 256, 0, stream>>>(x, xclb);

    // y1 = lrelu(conv(x, W1, b1)) -> channel-last bf16
    conv_mfma_kernel<true><<<dim3(T_ * H_ * 4), 256, 0, stream>>>(
        xclb, wT1b, b1, y1b, nullptr, 64);

    // offsets = conv(y1, W_off, b_off) -> channel-first fp32 (54 ch)
    conv_mfma_kernel<false><<<dim3(T_ * H_ * 4), 256, 0, stream>>>(
        y1b, wToffb, boff, nullptr, offcf, NOFF);

    // y2 = lrelu(deform(y1, offsets, Wd, bd)) + (Wr·x + br)
    deform_mfma_kernel<<<dim3(T_ * H_ * 4), 256, 0, stream>>>(
        y1b, offcf, wdTb, bd, xclb, wrTb, br, out);
}

// Round 5
// 262.065 us; speedup vs baseline: 1.8004x; 1.8004x over previous
//
#include <hip/hip_runtime.h>
#include <hip/hip_bf16.h>

// Problem constants (B=1)
#define T_ 8
#define H_ 64
#define W_ 64
#define C_ 64
#define HW_ (H_ * W_)          // 4096
#define THW_ (T_ * H_ * W_)    // 32768
#define KTAPS 27
#define KDIM (C_ * KTAPS)      // 1728
#define NOFF 54
#define CHS 70                 // padded channel stride in LDS (bf16 elems): kills bank conflicts

typedef __bf16 bf16x8 __attribute__((ext_vector_type(8)));
typedef float floatx4 __attribute__((ext_vector_type(4)));

// ---------------------------------------------------------------------------
// prep v2: per-cout LDS transpose, coalesced reads AND writes.
//  Grid 64 blocks (one per cout). wT*[co][tap*64+cin] = W*[co][cin][tap].
// ---------------------------------------------------------------------------
__global__ __launch_bounds__(256) void prep_kernel(
    const float* __restrict__ w1, const float* __restrict__ woff,
    const float* __restrict__ wd, const float* __restrict__ wr,
    __hip_bfloat16* __restrict__ wT1b, __hip_bfloat16* __restrict__ wToffb,
    __hip_bfloat16* __restrict__ wdTb, __hip_bfloat16* __restrict__ wrTb) {
    __shared__ float s1[KDIM], s2[KDIM], s3[KDIM];
    const int co = blockIdx.x;
    const int tid = threadIdx.x;
    for (int j = tid; j < KDIM; j += 256) {
        s1[j] = w1[co * KDIM + j];
        s2[j] = (co < NOFF) ? woff[co * KDIM + j] : 0.f;
        s3[j] = wd[co * KDIM + j];
    }
    __syncthreads();
    for (int j = tid; j < KDIM; j += 256) {       // j = tap*64 + cin
        int tap = j >> 6, cin = j & 63;
        int src = cin * KTAPS + tap;
        wT1b[co * KDIM + j] = __float2bfloat16(s1[src]);
        wToffb[co * KDIM + j] = __float2bfloat16(s2[src]);
        wdTb[co * KDIM + j] = __float2bfloat16(s3[src]);
    }
    if (tid < C_) wrTb[co * C_ + tid] = __float2bfloat16(wr[co * C_ + tid]);
}

// ---------------------------------------------------------------------------
// x (64,T,H,W) fp32 cf -> xcl (T,H,W,64) bf16 cl, via LDS 64x64 transpose tile
// ---------------------------------------------------------------------------
__global__ __launch_bounds__(256) void to_cl_kernel(const float* __restrict__ x,
                                                    __hip_bfloat16* __restrict__ xcl) {
    __shared__ float tile[64][65];
    const int pos0 = blockIdx.x * 64;
    const int tid = threadIdx.x;
    for (int i = tid; i < 4096; i += 256) {          // coalesced read: p contiguous
        int ch = i >> 6, p = i & 63;
        tile[ch][p] = x[ch * THW_ + pos0 + p];
    }
    __syncthreads();
    for (int i = tid; i < 4096; i += 256) {          // coalesced write: ch contiguous
        int p = i >> 6, ch = i & 63;
        xcl[(pos0 + p) * C_ + ch] = __float2bfloat16(tile[ch][p]);
    }
}

// ---------------------------------------------------------------------------
// MFMA implicit-GEMM 3x3x3 conv, pad=1, LDS row staging + dbuf prefetch.
//  Block = (t,h): 64 positions x 64 couts. 4 waves x 16 couts, m=4 subtiles.
//  Per (kt,kh) row: cooperative stage into LDS (66-pos halo, zero-padded),
//  then 3 kw taps: A-frags via conflict-free ds_read_b128, B reused over m.
// ---------------------------------------------------------------------------
template <bool CONV1>
__global__ __launch_bounds__(256) void conv_mfma_kernel(
    const __hip_bfloat16* __restrict__ in_cl,
    const __hip_bfloat16* __restrict__ wT,
    const float* __restrict__ bias,
    __hip_bfloat16* __restrict__ out_cl_b16, // CONV1: (T,H,W,64)
    float* __restrict__ out_cf,              // !CONV1: (NCO,T,H,W)
    int nco) {
    __shared__ float smem[4620];             // 18480 B: 2 x (66*70) bf16, reused as ts
    __hip_bfloat16* Ab = (__hip_bfloat16*)smem;   // Ab + (r&1)*66*CHS

    const int tid = threadIdx.x;
    const int wv = tid >> 6;
    const int lane = tid & 63;
    const int l15 = lane & 15;
    const int quad = lane >> 4;
    const int h = blockIdx.x & 63;
    const int t = blockIdx.x >> 6;
    const int n = wv * 16 + l15;             // this lane's cout
    const int cpos = tid >> 2;               // cooperative: position 0..63
    const int cchunk = tid & 3;              // 16-ch chunk

    // zero the halo positions (buffer idx 0 and 65) in both buffers, once
    if (tid < 32) {
        const int buf = tid >> 4, idx = tid & 15;
        const int p = (idx < 8) ? 0 : 65, c8 = idx & 7;
        *(bf16x8*)&Ab[buf * 66 * CHS + p * CHS + c8 * 8] = (bf16x8){};
    }

    floatx4 acc[4];
#pragma unroll
    for (int m = 0; m < 4; ++m) acc[m] = (floatx4){0.f, 0.f, 0.f, 0.f};

    const int ktlo = (t == 0) ? 1 : 0;
    const int kthi = (t == T_ - 1) ? 2 : 3;
    const int nr = (kthi - ktlo) * 3;

    // row loader -> registers
    bf16x8 ra = {}, rb = {};
    auto load_row = [&](int r, bf16x8& a, bf16x8& b) {
        const int kt = ktlo + r / 3, kh = r % 3;
        const int h_in = h - 1 + kh;
        const int t_in = t - 1 + kt;
        if ((unsigned)h_in < H_) {
            const __hip_bfloat16* p = in_cl + ((t_in * HW_ + h_in * W_) + cpos) * C_ + cchunk * 16;
            a = *(const bf16x8*)(p);
            b = *(const bf16x8*)(p + 8);
        } else {
            a = (bf16x8){};
            b = (bf16x8){};
        }
    };
    load_row(0, ra, rb);

    for (int r = 0; r < nr; ++r) {
        __hip_bfloat16* buf = Ab + (r & 1) * 66 * CHS;
        *(bf16x8*)&buf[(cpos + 1) * CHS + cchunk * 16] = ra;
        *(bf16x8*)&buf[(cpos + 1) * CHS + cchunk * 16 + 8] = rb;
        if (r + 1 < nr) load_row(r + 1, ra, rb);      // prefetch (latency spans barrier+MFMA)
        __syncthreads();

        const int kt = ktlo + r / 3, kh = r % 3;
        const int tapb = kt * 9 + kh * 3;
#pragma unroll
        for (int kw = 0; kw < 3; ++kw) {
            const __hip_bfloat16* wB = wT + n * KDIM + (tapb + kw) * 64 + quad * 8;
            const bf16x8 b0 = *(const bf16x8*)(wB);
            const bf16x8 b1 = *(const bf16x8*)(wB + 32);
#pragma unroll
            for (int m = 0; m < 4; ++m) {
                const __hip_bfloat16* ap = buf + (m * 16 + l15 + kw) * CHS + quad * 8;
                const bf16x8 a0 = *(const bf16x8*)(ap);
                const bf16x8 a1 = *(const bf16x8*)(ap + 32);
                acc[m] = __builtin_amdgcn_mfma_f32_16x16x32_bf16(a0, b0, acc[m], 0, 0, 0);
                acc[m] = __builtin_amdgcn_mfma_f32_16x16x32_bf16(a1, b1, acc[m], 0, 0, 0);
            }
        }
    }

    const int posbase = t * HW_ + h * W_;

    if constexpr (CONV1) {
        __syncthreads();                              // done reading Ab; reuse as ts
        float* ts = smem;                             // [64 pos][68 ch]
        const float bv = bias[n];
#pragma unroll
        for (int m = 0; m < 4; ++m)
#pragma unroll
            for (int r = 0; r < 4; ++r) {
                float v = acc[m][r] + bv;
                v = (v >= 0.f) ? v : 0.01f * v;       // lrelu
                ts[(m * 16 + quad * 4 + r) * 68 + n] = v;
            }
        __syncthreads();
#pragma unroll
        for (int c = 0; c < 4; ++c) {
            const int flat4 = c * 256 + tid;          // 1024 4-float chunks
            const int w = flat4 >> 4, cg = flat4 & 15;
            const float4 v4 = *(const float4*)&ts[w * 68 + cg * 4];
            __hip_bfloat16 hb[4] = {__float2bfloat16(v4.x), __float2bfloat16(v4.y),
                                    __float2bfloat16(v4.z), __float2bfloat16(v4.w)};
            *(uint2*)&out_cl_b16[(posbase + w) * C_ + cg * 4] = *(const uint2*)hb;
        }
    } else {
        if (n < nco) {
            const float bv = bias[n];
#pragma unroll
            for (int m = 0; m < 4; ++m) {
                floatx4 v = acc[m];
                v[0] += bv; v[1] += bv; v[2] += bv; v[3] += bv;
                *(floatx4*)&out_cf[n * THW_ + posbase + m * 16 + quad * 4] = v;
            }
        }
    }
}

// ---------------------------------------------------------------------------
// MFMA deformable conv, cooperative LDS-staged A + software pipeline.
//  Block = (t,h): 64 pos x 64 couts. Per tap: 256 threads gather+blend the
//  full 64x64 A-panel (each thread: 16 ch of one position) into dbuf LDS;
//  offsets prefetched 2 taps ahead, gathers issued 1 tap ahead.
//  + bias + lrelu + fused 1x1 MFMA residual.
// ---------------------------------------------------------------------------
struct Gath {
    bf16x8 c00a, c00b, c01a, c01b, c10a, c10b, c11a, c11b;
    float w00, w01, w10, w11;
};

__global__ __launch_bounds__(256) void deform_mfma_kernel(
    const __hip_bfloat16* __restrict__ y1b, const float* __restrict__ off,
    const __hip_bfloat16* __restrict__ wdTb, const float* __restrict__ bd,
    const __hip_bfloat16* __restrict__ xclb, const __hip_bfloat16* __restrict__ wrTb,
    const float* __restrict__ br, float* __restrict__ out) {
    __shared__ __hip_bfloat16 Abuf[2][64 * CHS];     // 17920 B

    const int tid = threadIdx.x;
    const int wv = tid >> 6;
    const int lane = tid & 63;
    const int l15 = lane & 15;
    const int quad = lane >> 4;
    const int h = blockIdx.x & 63;
    const int t = blockIdx.x >> 6;
    const int n = wv * 16 + l15;             // this lane's cout
    const int posbase = t * HW_ + h * W_;
    const int cpos = tid >> 2;               // cooperative: position 0..63
    const int cchunk = tid & 3;              // 16-ch chunk

    floatx4 acc[4], racc[4];
#pragma unroll
    for (int m = 0; m < 4; ++m) {
        acc[m] = (floatx4){0.f, 0.f, 0.f, 0.f};
        racc[m] = (floatx4){0.f, 0.f, 0.f, 0.f};
    }

    // ---- residual 1x1 conv on x (independent; issues early) ----
    {
        const __hip_bfloat16* wrB = wrTb + n * C_ + quad * 8;
        const bf16x8 rb0 = *(const bf16x8*)(wrB);
        const bf16x8 rb1 = *(const bf16x8*)(wrB + 32);
#pragma unroll
        for (int m = 0; m < 4; ++m) {
            const __hip_bfloat16* ap = xclb + (posbase + m * 16 + l15) * C_ + quad * 8;
            const bf16x8 a0 = *(const bf16x8*)(ap);
            const bf16x8 a1 = *(const bf16x8*)(ap + 32);
            racc[m] = __builtin_amdgcn_mfma_f32_16x16x32_bf16(a0, rb0, racc[m], 0, 0, 0);
            racc[m] = __builtin_amdgcn_mfma_f32_16x16x32_bf16(a1, rb1, racc[m], 0, 0, 0);
        }
    }

    const int k0 = (t == 0) ? 9 : 0;
    const int k1 = (t == T_ - 1) ? 18 : KTAPS;

    auto load_off = [&](int k, float& dh, float& dw) {
        dh = off[(2 * k) * THW_ + posbase + cpos];
        dw = off[(2 * k + 1) * THW_ + posbase + cpos];
    };
    auto gather = [&](int k, float dh, float dw, Gath& g) {
        const int kt = k / 9, kh = (k / 3) % 3, kw = k % 3;
        const int t_in = t - 1 + kt;
        const float hs = (float)(h - 1 + kh) + dh;
        const float wsv = (float)(cpos - 1 + kw) + dw;
        const float h0f = floorf(hs), w0f = floorf(wsv);
        const float fh = hs - h0f, fw = wsv - w0f;
        const int h0i = (int)h0f, w0i = (int)w0f;
        const int h1i = h0i + 1, w1i = w0i + 1;
        const float m_h0 = ((unsigned)h0i < H_) ? 1.f : 0.f;
        const float m_h1 = ((unsigned)h1i < H_) ? 1.f : 0.f;
        const float m_w0 = ((unsigned)w0i < W_) ? 1.f : 0.f;
        const float m_w1 = ((unsigned)w1i < W_) ? 1.f : 0.f;
        g.w00 = (1.f - fh) * (1.f - fw) * m_h0 * m_w0;
        g.w01 = (1.f - fh) * fw * m_h0 * m_w1;
        g.w10 = fh * (1.f - fw) * m_h1 * m_w0;
        g.w11 = fh * fw * m_h1 * m_w1;
        const int h0c = min(max(h0i, 0), H_ - 1);
        const int h1c = min(max(h1i, 0), H_ - 1);
        const int w0c = min(max(w0i, 0), W_ - 1);
        const int w1c = min(max(w1i, 0), W_ - 1);
        const int tb = t_in * HW_;
        const __hip_bfloat16* p00 = y1b + (tb + h0c * W_ + w0c) * C_ + cchunk * 16;
        const __hip_bfloat16* p01 = y1b + (tb + h0c * W_ + w1c) * C_ + cchunk * 16;
        const __hip_bfloat16* p10 = y1b + (tb + h1c * W_ + w0c) * C_ + cchunk * 16;
        const __hip_bfloat16* p11 = y1b + (tb + h1c * W_ + w1c) * C_ + cchunk * 16;
        g.c00a = *(const bf16x8*)(p00); g.c00b = *(const bf16x8*)(p00 + 8);
        g.c01a = *(const bf16x8*)(p01); g.c01b = *(const bf16x8*)(p01 + 8);
        g.c10a = *(const bf16x8*)(p10); g.c10b = *(const bf16x8*)(p10 + 8);
        g.c11a = *(const bf16x8*)(p11); g.c11b = *(const bf16x8*)(p11 + 8);
    };
    auto blend = [&](const Gath& g, bf16x8& oa, bf16x8& ob) {
        union U { bf16x8 v; __hip_bfloat16 e[8]; };
        U a00, a01, a10, a11, r;
#pragma unroll
        for (int half = 0; half < 2; ++half) {
            a00.v = half ? g.c00b : g.c00a;
            a01.v = half ? g.c01b : g.c01a;
            a10.v = half ? g.c10b : g.c10a;
            a11.v = half ? g.c11b : g.c11a;
#pragma unroll
            for (int j = 0; j < 8; ++j) {
                float f = g.w00 * __bfloat162float(a00.e[j]) + g.w01 * __bfloat162float(a01.e[j]) +
                          g.w10 * __bfloat162float(a10.e[j]) + g.w11 * __bfloat162float(a11.e[j]);
                r.e[j] = __float2bfloat16(f);
            }
            if (half) ob = r.v; else oa = r.v;
        }
    };

    // ---- pipeline prologue ----
    float dh_c, dw_c, dh_n = 0.f, dw_n = 0.f;
    Gath g;
    bf16x8 blA, blB;
    load_off(k0, dh_c, dw_c);
    if (k0 + 1 < k1) load_off(k0 + 1, dh_n, dw_n);
    gather(k0, dh_c, dw_c, g);
    blend(g, blA, blB);

    // ---- main loop: 1 barrier per tap ----
    for (int k = k0; k < k1; ++k) {
        __hip_bfloat16* buf = Abuf[k & 1];
        *(bf16x8*)&buf[cpos * CHS + cchunk * 16] = blA;
        *(bf16x8*)&buf[cpos * CHS + cchunk * 16 + 8] = blB;
        if (k + 1 < k1) {
            const float gdh = dh_n, gdw = dw_n;
            if (k + 2 < k1) load_off(k + 2, dh_n, dw_n);
            gather(k + 1, gdh, gdw, g);               // loads span barrier + MFMA phase
        }
        __syncthreads();

        const __hip_bfloat16* wB = wdTb + n * KDIM + k * 64 + quad * 8;
        const bf16x8 b0 = *(const bf16x8*)(wB);
        const bf16x8 b1 = *(const bf16x8*)(wB + 32);
#pragma unroll
        for (int m = 0; m < 4; ++m) {
            const __hip_bfloat16* ap = buf + (m * 16 + l15) * CHS + quad * 8;
            const bf16x8 a0 = *(const bf16x8*)(ap);
            const bf16x8 a1 = *(const bf16x8*)(ap + 32);
            acc[m] = __builtin_amdgcn_mfma_f32_16x16x32_bf16(a0, b0, acc[m], 0, 0, 0);
            acc[m] = __builtin_amdgcn_mfma_f32_16x16x32_bf16(a1, b1, acc[m], 0, 0, 0);
        }
        if (k + 1 < k1) blend(g, blA, blB);
    }

    // ---- epilogue: lrelu(deform + bd) + (residual + br) ----
    const float bdv = bd[n];
    const float brv = br[n];
#pragma unroll
    for (int m = 0; m < 4; ++m) {
        floatx4 o;
#pragma unroll
        for (int r = 0; r < 4; ++r) {
            float v = acc[m][r] + bdv;
            v = (v >= 0.f) ? v : 0.01f * v;
            o[r] = v + racc[m][r] + brv;
        }
        *(floatx4*)&out[n * THW_ + posbase + m * 16 + quad * 4] = o;
    }
}

// ---------------------------------------------------------------------------
extern "C" void kernel_launch(void* const* d_in, const int* in_sizes, int n_in,
                              void* d_out, int out_size, void* d_ws, size_t ws_size,
                              hipStream_t stream) {
    const float* x    = (const float*)d_in[0];
    const float* W1   = (const float*)d_in[1];
    const float* b1   = (const float*)d_in[2];
    const float* Woff = (const float*)d_in[3];
    const float* boff = (const float*)d_in[4];
    const float* Wd   = (const float*)d_in[5];
    const float* bd   = (const float*)d_in[6];
    const float* Wr   = (const float*)d_in[7];
    const float* br   = (const float*)d_in[8];
    float* out = (float*)d_out;

    float* ws = (float*)d_ws;
    float* offcf = ws;                                         // 1,769,472 f
    __hip_bfloat16* xclb   = (__hip_bfloat16*)(ws + 1769472);  // 2,097,152 bf16
    __hip_bfloat16* y1b    = (__hip_bfloat16*)(ws + 2818048);  // 2,097,152 bf16
    __hip_bfloat16* wT1b   = (__hip_bfloat16*)(ws + 3866624);  //   110,592 bf16
    __hip_bfloat16* wToffb = (__hip_bfloat16*)(ws + 3921920);  //   110,592 bf16
    __hip_bfloat16* wdTb   = (__hip_bfloat16*)(ws + 3977216);  //   110,592 bf16
    __hip_bfloat16* wrTb   = (__hip_bfloat16*)(ws + 4032512);  //     4,096 bf16
    // total ~16.1 MB

    prep_kernel<<<C_, 256, 0, stream>>>(
        W1, Woff, Wd, Wr, wT1b, wToffb, wdTb, wrTb);

    to_cl_kernel<<<THW_ / 64, 256, 0, stream>>>(x, xclb);

    // y1 = lrelu(conv(x, W1, b1)) -> channel-last bf16
    conv_mfma_kernel<true><<<dim3(T_ * H_), 256, 0, stream>>>(
        xclb, wT1b, b1, y1b, nullptr, 64);

    // offsets = conv(y1, W_off, b_off) -> channel-first fp32 (54 ch)
    conv_mfma_kernel<false><<<dim3(T_ * H_), 256, 0, stream>>>(
        y1b, wToffb, boff, nullptr, offcf, NOFF);

    // y2 = lrelu(deform(y1, offsets, Wd, bd)) + (Wr·x + br)
    deform_mfma_kernel<<<dim3(T_ * H_), 256, 0, stream>>>(
        y1b, offcf, wdTb, bd, xclb, wrTb, br, out);
}

// Round 6
// 246.192 us; speedup vs baseline: 1.9164x; 1.0645x over previous
//
#include <hip/hip_runtime.h>
#include <hip/hip_bf16.h>

// Problem constants (B=1)
#define T_ 8
#define H_ 64
#define W_ 64
#define C_ 64
#define HW_ (H_ * W_)          // 4096
#define THW_ (T_ * H_ * W_)    // 32768
#define KTAPS 27
#define KDIM (C_ * KTAPS)      // 1728
#define NOFF 54
#define CHS 70                 // padded channel stride in LDS (bf16): stride 140B, gcd(35,32)=1

typedef __bf16 bf16x8 __attribute__((ext_vector_type(8)));
typedef float floatx4 __attribute__((ext_vector_type(4)));

// ---------------------------------------------------------------------------
// prep: per-cout LDS transpose, coalesced reads AND writes.
// ---------------------------------------------------------------------------
__global__ __launch_bounds__(256) void prep_kernel(
    const float* __restrict__ w1, const float* __restrict__ woff,
    const float* __restrict__ wd, const float* __restrict__ wr,
    __hip_bfloat16* __restrict__ wT1b, __hip_bfloat16* __restrict__ wToffb,
    __hip_bfloat16* __restrict__ wdTb, __hip_bfloat16* __restrict__ wrTb) {
    __shared__ float s1[KDIM], s2[KDIM], s3[KDIM];
    const int co = blockIdx.x;
    const int tid = threadIdx.x;
    for (int j = tid; j < KDIM; j += 256) {
        s1[j] = w1[co * KDIM + j];
        s2[j] = (co < NOFF) ? woff[co * KDIM + j] : 0.f;
        s3[j] = wd[co * KDIM + j];
    }
    __syncthreads();
    for (int j = tid; j < KDIM; j += 256) {       // j = tap*64 + cin
        int tap = j >> 6, cin = j & 63;
        int src = cin * KTAPS + tap;
        wT1b[co * KDIM + j] = __float2bfloat16(s1[src]);
        wToffb[co * KDIM + j] = __float2bfloat16(s2[src]);
        wdTb[co * KDIM + j] = __float2bfloat16(s3[src]);
    }
    if (tid < C_) wrTb[co * C_ + tid] = __float2bfloat16(wr[co * C_ + tid]);
}

// ---------------------------------------------------------------------------
// x (64,T,H,W) fp32 cf -> xcl (T,H,W,64) bf16 cl, via LDS 64x64 transpose tile
// ---------------------------------------------------------------------------
__global__ __launch_bounds__(256) void to_cl_kernel(const float* __restrict__ x,
                                                    __hip_bfloat16* __restrict__ xcl) {
    __shared__ float tile[64][65];
    const int pos0 = blockIdx.x * 64;
    const int tid = threadIdx.x;
    for (int i = tid; i < 4096; i += 256) {          // coalesced read: p contiguous
        int ch = i >> 6, p = i & 63;
        tile[ch][p] = x[ch * THW_ + pos0 + p];
    }
    __syncthreads();
    for (int i = tid; i < 4096; i += 256) {          // coalesced write: ch contiguous
        int p = i >> 6, ch = i & 63;
        xcl[(pos0 + p) * C_ + ch] = __float2bfloat16(tile[ch][p]);
    }
}

// ---------------------------------------------------------------------------
// MFMA implicit-GEMM 3x3x3 conv, pad=1, LDS row staging + dbuf prefetch.
//  Block = (t,h,w-half): 32 positions x 64 couts, grid T*H*2 = 1024.
//  4 waves x 16 couts, m=2 subtiles. Per (kt,kh) row: threads 0..135 stage
//  34-slot halo row (16 ch each) into dbuf LDS; 3 kw taps read shifted
//  A-frags via conflict-free ds_read_b128, B reused over m.
// ---------------------------------------------------------------------------
template <bool CONV1>
__global__ __launch_bounds__(256) void conv_mfma_kernel(
    const __hip_bfloat16* __restrict__ in_cl,
    const __hip_bfloat16* __restrict__ wT,
    const float* __restrict__ bias,
    __hip_bfloat16* __restrict__ out_cl_b16, // CONV1: (T,H,W,64)
    float* __restrict__ out_cf,              // !CONV1: (NCO,T,H,W)
    int nco) {
    __shared__ float smem[2380];             // 9520 B: 2 x (34*70) bf16; reused as ts[32][68]
    __hip_bfloat16* Ab = (__hip_bfloat16*)smem;

    const int tid = threadIdx.x;
    const int wv = tid >> 6;
    const int lane = tid & 63;
    const int l15 = lane & 15;
    const int quad = lane >> 4;
    const int wh = blockIdx.x & 1;
    const int h = (blockIdx.x >> 1) & 63;
    const int t = blockIdx.x >> 7;
    const int w0 = wh * 32;
    const int n = wv * 16 + l15;             // this lane's cout
    const int slot = tid >> 2;               // staging: 34 slots, threads 0..135
    const int c16 = tid & 3;                 // 16-ch chunk
    const bool stager = tid < 136;

    floatx4 acc[2];
#pragma unroll
    for (int m = 0; m < 2; ++m) acc[m] = (floatx4){0.f, 0.f, 0.f, 0.f};

    const int ktlo = (t == 0) ? 1 : 0;
    const int kthi = (t == T_ - 1) ? 2 : 3;
    const int nr = (kthi - ktlo) * 3;

    // row loader -> registers (threads 0..135 only)
    bf16x8 ra = {}, rb = {};
    auto load_row = [&](int r, bf16x8& a, bf16x8& b) {
        a = (bf16x8){};
        b = (bf16x8){};
        if (!stager) return;
        const int kt = ktlo + r / 3, kh = r % 3;
        const int h_in = h - 1 + kh;
        const int t_in = t - 1 + kt;
        const int w_in = w0 - 1 + slot;
        if ((unsigned)h_in < H_ && (unsigned)w_in < W_) {
            const __hip_bfloat16* p = in_cl + ((t_in * HW_ + h_in * W_) + w_in) * C_ + c16 * 16;
            a = *(const bf16x8*)(p);
            b = *(const bf16x8*)(p + 8);
        }
    };
    load_row(0, ra, rb);

    for (int r = 0; r < nr; ++r) {
        __hip_bfloat16* buf = Ab + (r & 1) * 34 * CHS;
        if (stager) {
            *(bf16x8*)&buf[slot * CHS + c16 * 16] = ra;
            *(bf16x8*)&buf[slot * CHS + c16 * 16 + 8] = rb;
        }
        if (r + 1 < nr) load_row(r + 1, ra, rb);      // prefetch spans barrier+MFMA
        __syncthreads();

        const int kt = ktlo + r / 3, kh = r % 3;
        const int tapb = kt * 9 + kh * 3;
#pragma unroll
        for (int kw = 0; kw < 3; ++kw) {
            const __hip_bfloat16* wB = wT + n * KDIM + (tapb + kw) * 64 + quad * 8;
            const bf16x8 b0 = *(const bf16x8*)(wB);
            const bf16x8 b1 = *(const bf16x8*)(wB + 32);
#pragma unroll
            for (int m = 0; m < 2; ++m) {
                const __hip_bfloat16* ap = buf + (m * 16 + l15 + kw) * CHS + quad * 8;
                const bf16x8 a0 = *(const bf16x8*)(ap);
                const bf16x8 a1 = *(const bf16x8*)(ap + 32);
                acc[m] = __builtin_amdgcn_mfma_f32_16x16x32_bf16(a0, b0, acc[m], 0, 0, 0);
                acc[m] = __builtin_amdgcn_mfma_f32_16x16x32_bf16(a1, b1, acc[m], 0, 0, 0);
            }
        }
        __syncthreads();                              // protect dbuf (2-deep) reuse
    }

    const int posbase = t * HW_ + h * W_ + w0;

    if constexpr (CONV1) {
        float* ts = smem;                             // [32 pos][68 ch]
        const float bv = bias[n];
#pragma unroll
        for (int m = 0; m < 2; ++m)
#pragma unroll
            for (int r = 0; r < 4; ++r) {
                float v = acc[m][r] + bv;
                v = (v >= 0.f) ? v : 0.01f * v;       // lrelu
                ts[(m * 16 + quad * 4 + r) * 68 + n] = v;
            }
        __syncthreads();
#pragma unroll
        for (int c = 0; c < 2; ++c) {
            const int flat4 = c * 256 + tid;          // 512 4-float chunks
            const int w = flat4 >> 4, cg = flat4 & 15;
            const float4 v4 = *(const float4*)&ts[w * 68 + cg * 4];
            __hip_bfloat16 hb[4] = {__float2bfloat16(v4.x), __float2bfloat16(v4.y),
                                    __float2bfloat16(v4.z), __float2bfloat16(v4.w)};
            *(uint2*)&out_cl_b16[(posbase + w) * C_ + cg * 4] = *(const uint2*)hb;
        }
    } else {
        if (n < nco) {
            const float bv = bias[n];
#pragma unroll
            for (int m = 0; m < 2; ++m) {
                floatx4 v = acc[m];
                v[0] += bv; v[1] += bv; v[2] += bv; v[3] += bv;
                *(floatx4*)&out_cf[n * THW_ + posbase + m * 16 + quad * 4] = v;
            }
        }
    }
}

// ---------------------------------------------------------------------------
// MFMA deformable conv, cooperative LDS-staged A + software pipeline.
//  Block = (t,h,w-half): 32 pos x 64 couts, grid 1024. Per tap: 256 threads
//  gather+blend the 32x64 A-panel (each thread: 8 ch of one position) into
//  dbuf LDS; offsets prefetched 2 taps ahead, gathers 1 tap ahead.
//  + bias + lrelu + fused 1x1 MFMA residual.
// ---------------------------------------------------------------------------
struct Gath {
    bf16x8 c00, c01, c10, c11;
    float w00, w01, w10, w11;
};

__global__ __launch_bounds__(256) void deform_mfma_kernel(
    const __hip_bfloat16* __restrict__ y1b, const float* __restrict__ off,
    const __hip_bfloat16* __restrict__ wdTb, const float* __restrict__ bd,
    const __hip_bfloat16* __restrict__ xclb, const __hip_bfloat16* __restrict__ wrTb,
    const float* __restrict__ br, float* __restrict__ out) {
    __shared__ __hip_bfloat16 Abuf[2][32 * CHS];     // 8960 B

    const int tid = threadIdx.x;
    const int wv = tid >> 6;
    const int lane = tid & 63;
    const int l15 = lane & 15;
    const int quad = lane >> 4;
    const int wh = blockIdx.x & 1;
    const int h = (blockIdx.x >> 1) & 63;
    const int t = blockIdx.x >> 7;
    const int w0 = wh * 32;
    const int n = wv * 16 + l15;             // this lane's cout
    const int posbase = t * HW_ + h * W_ + w0;
    const int cpos = tid >> 3;               // cooperative: position 0..31
    const int c8 = tid & 7;                  // 8-ch chunk

    floatx4 acc[2], racc[2];
#pragma unroll
    for (int m = 0; m < 2; ++m) {
        acc[m] = (floatx4){0.f, 0.f, 0.f, 0.f};
        racc[m] = (floatx4){0.f, 0.f, 0.f, 0.f};
    }

    // ---- residual 1x1 conv on x (independent; issues early) ----
    {
        const __hip_bfloat16* wrB = wrTb + n * C_ + quad * 8;
        const bf16x8 rb0 = *(const bf16x8*)(wrB);
        const bf16x8 rb1 = *(const bf16x8*)(wrB + 32);
#pragma unroll
        for (int m = 0; m < 2; ++m) {
            const __hip_bfloat16* ap = xclb + (posbase + m * 16 + l15) * C_ + quad * 8;
            const bf16x8 a0 = *(const bf16x8*)(ap);
            const bf16x8 a1 = *(const bf16x8*)(ap + 32);
            racc[m] = __builtin_amdgcn_mfma_f32_16x16x32_bf16(a0, rb0, racc[m], 0, 0, 0);
            racc[m] = __builtin_amdgcn_mfma_f32_16x16x32_bf16(a1, rb1, racc[m], 0, 0, 0);
        }
    }

    const int k0 = (t == 0) ? 9 : 0;
    const int k1 = (t == T_ - 1) ? 18 : KTAPS;

    auto load_off = [&](int k, float& dh, float& dw) {
        dh = off[(2 * k) * THW_ + posbase + cpos];
        dw = off[(2 * k + 1) * THW_ + posbase + cpos];
    };
    auto gather = [&](int k, float dh, float dw, Gath& g) {
        const int kt = k / 9, kh = (k / 3) % 3, kw = k % 3;
        const int t_in = t - 1 + kt;
        const float hs = (float)(h - 1 + kh) + dh;
        const float wsv = (float)(w0 + cpos - 1 + kw) + dw;
        const float h0f = floorf(hs), w0f = floorf(wsv);
        const float fh = hs - h0f, fw = wsv - w0f;
        const int h0i = (int)h0f, w0i = (int)w0f;
        const int h1i = h0i + 1, w1i = w0i + 1;
        const float m_h0 = ((unsigned)h0i < H_) ? 1.f : 0.f;
        const float m_h1 = ((unsigned)h1i < H_) ? 1.f : 0.f;
        const float m_w0 = ((unsigned)w0i < W_) ? 1.f : 0.f;
        const float m_w1 = ((unsigned)w1i < W_) ? 1.f : 0.f;
        g.w00 = (1.f - fh) * (1.f - fw) * m_h0 * m_w0;
        g.w01 = (1.f - fh) * fw * m_h0 * m_w1;
        g.w10 = fh * (1.f - fw) * m_h1 * m_w0;
        g.w11 = fh * fw * m_h1 * m_w1;
        const int h0c = min(max(h0i, 0), H_ - 1);
        const int h1c = min(max(h1i, 0), H_ - 1);
        const int w0c = min(max(w0i, 0), W_ - 1);
        const int w1c = min(max(w1i, 0), W_ - 1);
        const int tb = t_in * HW_;
        g.c00 = *(const bf16x8*)(y1b + (tb + h0c * W_ + w0c) * C_ + c8 * 8);
        g.c01 = *(const bf16x8*)(y1b + (tb + h0c * W_ + w1c) * C_ + c8 * 8);
        g.c10 = *(const bf16x8*)(y1b + (tb + h1c * W_ + w0c) * C_ + c8 * 8);
        g.c11 = *(const bf16x8*)(y1b + (tb + h1c * W_ + w1c) * C_ + c8 * 8);
    };
    auto blend = [&](const Gath& g, bf16x8& o) {
        union U { bf16x8 v; __hip_bfloat16 e[8]; };
        U a00, a01, a10, a11, r;
        a00.v = g.c00; a01.v = g.c01; a10.v = g.c10; a11.v = g.c11;
#pragma unroll
        for (int j = 0; j < 8; ++j) {
            float f = g.w00 * __bfloat162float(a00.e[j]) + g.w01 * __bfloat162float(a01.e[j]) +
                      g.w10 * __bfloat162float(a10.e[j]) + g.w11 * __bfloat162float(a11.e[j]);
            r.e[j] = __float2bfloat16(f);
        }
        o = r.v;
    };

    // ---- pipeline prologue ----
    float dh_c, dw_c, dh_n = 0.f, dw_n = 0.f;
    Gath g;
    bf16x8 bl;
    load_off(k0, dh_c, dw_c);
    if (k0 + 1 < k1) load_off(k0 + 1, dh_n, dw_n);
    gather(k0, dh_c, dw_c, g);
    blend(g, bl);

    // ---- main loop: 1 barrier per tap ----
    for (int k = k0; k < k1; ++k) {
        __hip_bfloat16* buf = Abuf[k & 1];
        *(bf16x8*)&buf[cpos * CHS + c8 * 8] = bl;
        if (k + 1 < k1) {
            const float gdh = dh_n, gdw = dw_n;
            if (k + 2 < k1) load_off(k + 2, dh_n, dw_n);
            gather(k + 1, gdh, gdw, g);               // loads span barrier + MFMA phase
        }
        __syncthreads();

        const __hip_bfloat16* wB = wdTb + n * KDIM + k * 64 + quad * 8;
        const bf16x8 b0 = *(const bf16x8*)(wB);
        const bf16x8 b1 = *(const bf16x8*)(wB + 32);
#pragma unroll
        for (int m = 0; m < 2; ++m) {
            const __hip_bfloat16* ap = buf + (m * 16 + l15) * CHS + quad * 8;
            const bf16x8 a0 = *(const bf16x8*)(ap);
            const bf16x8 a1 = *(const bf16x8*)(ap + 32);
            acc[m] = __builtin_amdgcn_mfma_f32_16x16x32_bf16(a0, b0, acc[m], 0, 0, 0);
            acc[m] = __builtin_amdgcn_mfma_f32_16x16x32_bf16(a1, b1, acc[m], 0, 0, 0);
        }
        if (k + 1 < k1) blend(g, bl);
    }

    // ---- epilogue: lrelu(deform + bd) + (residual + br) ----
    const float bdv = bd[n];
    const float brv = br[n];
#pragma unroll
    for (int m = 0; m < 2; ++m) {
        floatx4 o;
#pragma unroll
        for (int r = 0; r < 4; ++r) {
            float v = acc[m][r] + bdv;
            v = (v >= 0.f) ? v : 0.01f * v;
            o[r] = v + racc[m][r] + brv;
        }
        *(floatx4*)&out[n * THW_ + posbase + m * 16 + quad * 4] = o;
    }
}

// ---------------------------------------------------------------------------
extern "C" void kernel_launch(void* const* d_in, const int* in_sizes, int n_in,
                              void* d_out, int out_size, void* d_ws, size_t ws_size,
                              hipStream_t stream) {
    const float* x    = (const float*)d_in[0];
    const float* W1   = (const float*)d_in[1];
    const float* b1   = (const float*)d_in[2];
    const float* Woff = (const float*)d_in[3];
    const float* boff = (const float*)d_in[4];
    const float* Wd   = (const float*)d_in[5];
    const float* bd   = (const float*)d_in[6];
    const float* Wr   = (const float*)d_in[7];
    const float* br   = (const float*)d_in[8];
    float* out = (float*)d_out;

    float* ws = (float*)d_ws;
    float* offcf = ws;                                         // 1,769,472 f
    __hip_bfloat16* xclb   = (__hip_bfloat16*)(ws + 1769472);  // 2,097,152 bf16
    __hip_bfloat16* y1b    = (__hip_bfloat16*)(ws + 2818048);  // 2,097,152 bf16
    __hip_bfloat16* wT1b   = (__hip_bfloat16*)(ws + 3866624);  //   110,592 bf16
    __hip_bfloat16* wToffb = (__hip_bfloat16*)(ws + 3921920);  //   110,592 bf16
    __hip_bfloat16* wdTb   = (__hip_bfloat16*)(ws + 3977216);  //   110,592 bf16
    __hip_bfloat16* wrTb   = (__hip_bfloat16*)(ws + 4032512);  //     4,096 bf16
    // total ~16.1 MB

    prep_kernel<<<C_, 256, 0, stream>>>(
        W1, Woff, Wd, Wr, wT1b, wToffb, wdTb, wrTb);

    to_cl_kernel<<<THW_ / 64, 256, 0, stream>>>(x, xclb);

    // y1 = lrelu(conv(x, W1, b1)) -> channel-last bf16
    conv_mfma_kernel<true><<<dim3(T_ * H_ * 2), 256, 0, stream>>>(
        xclb, wT1b, b1, y1b, nullptr, 64);

    // offsets = conv(y1, W_off, b_off) -> channel-first fp32 (54 ch)
    conv_mfma_kernel<false><<<dim3(T_ * H_ * 2), 256, 0, stream>>>(
        y1b, wToffb, boff, nullptr, offcf, NOFF);

    // y2 = lrelu(deform(y1, offsets, Wd, bd)) + (Wr·x + br)
    deform_mfma_kernel<<<dim3(T_ * H_ * 2), 256, 0, stream>>>(
        y1b, offcf, wdTb, bd, xclb, wrTb, br, out);
}